// Round 6
// baseline (203.668 us; speedup 1.0000x reference)
//
#include <hip/hip_runtime.h>
#include <hip/hip_bf16.h>

#define N_NODES 20000
#define N_EDGES 640000
#define NRELS 20
#define RB 4
#define GEMM_BLOCKS 1565   // 313 tiles * 5 relation-groups
#define FILL_BLOCKS 2500   // 640000 / 256

typedef __attribute__((ext_vector_type(8))) short short8;
typedef __attribute__((ext_vector_type(8))) unsigned short ushort8;
typedef __attribute__((ext_vector_type(4))) float floatx4;
typedef unsigned short u16;
typedef unsigned int u32;

__device__ __forceinline__ float bf2f(u16 u){
  union { u32 i; float f; } v; v.i = ((u32)u) << 16; return v.f;
}
__device__ __forceinline__ u16 f2bf(float f){
  __hip_bfloat16 b = __float2bfloat16(f);
  return __builtin_bit_cast(u16, b);
}

// ---------------- K0: fused {cast h->bf16 + count + rank} | {w_rel} ----------
__global__ __launch_bounds__(256) void k_prep(
    const float* __restrict__ h, u16* __restrict__ hb,
    const int* __restrict__ dst, int* __restrict__ counts, int* __restrict__ rank,
    const float* __restrict__ weight, const float* __restrict__ w_comp,
    u16* __restrict__ wrelT){
  const int b = blockIdx.x;
  if (b < 2500){
    int tidg = b * 256 + threadIdx.x;
    int i = tidg * 4;
    float4 v = *(const float4*)(h + i);
    u16 o[4] = { f2bf(v.x), f2bf(v.y), f2bf(v.z), f2bf(v.w) };
    *(ushort4*)(hb + i) = *(ushort4*)o;
    rank[tidg] = atomicAdd(&counts[dst[tidg]], 1);
  } else {
    int f = (b - 2500) * 256 + threadIdx.x;      // < 20*128*128 exactly
    int i  = f & 127;
    int ro = f >> 7;
    int o  = ro & 127;
    int r  = ro >> 7;
    int q  = r * 128 + i;                        // reference reshape semantics
    int rr = q % 20, ii = q / 20;
    float acc = 0.f;
    #pragma unroll
    for (int bb = 0; bb < 8; ++bb)
      acc += w_comp[rr * 8 + bb] * weight[ii * 1024 + bb * 128 + o];
    wrelT[f] = f2bf(acc);                        // [r][o][i]
  }
}

// ---------------- K1: single-block exclusive scan of counts ------------------
__global__ __launch_bounds__(1024) void k_scan(const int* __restrict__ counts,
                                               int* __restrict__ offsets){
  __shared__ int sums[1024];
  const int t = threadIdx.x;
  const int base = t * 20;                       // 1024*20 >= 20000
  int loc[20]; int s = 0;
  #pragma unroll
  for (int j = 0; j < 20; ++j){
    int idx = base + j;
    int v = (idx < N_NODES) ? counts[idx] : 0;
    loc[j] = v; s += v;
  }
  sums[t] = s;
  __syncthreads();
  for (int off = 1; off < 1024; off <<= 1){
    int v = (t >= off) ? sums[t - off] : 0;
    __syncthreads();
    sums[t] += v;
    __syncthreads();
  }
  int run = (t == 0) ? 0 : sums[t - 1];
  #pragma unroll
  for (int j = 0; j < 20; ++j){
    int idx = base + j;
    if (idx < N_NODES){ offsets[idx] = run; run += loc[j]; }
  }
  if (t == 0) offsets[N_NODES] = N_EDGES;
}

// ---------------- K2: xW = h @ W_r (A-in-reg, swizzled B, direct store) ------
//                      + fused atomic-free CSR fill on trailing blocks
__global__ __launch_bounds__(256, 4) void k_gemm_fill(
    const u16* __restrict__ hb, const u16* __restrict__ wrelT, u16* __restrict__ xW,
    const int* __restrict__ dst, const int* __restrict__ srcv,
    const int* __restrict__ ety, const int* __restrict__ offs,
    const int* __restrict__ rank, int* __restrict__ gidx){
  if (blockIdx.x >= GEMM_BLOCKS){                // ---- fill role ----
    int e = (blockIdx.x - GEMM_BLOCKS) * 256 + threadIdx.x;
    if (e < N_EDGES){
      int p = offs[dst[e]] + rank[e];
      gidx[p] = ety[e] * N_NODES + srcv[e];      // precomputed gather row
    }
    return;
  }
  // ---- gemm role: 64-row tile x 4 relations ----
  __shared__ u16 Bs[128 * 128];                  // 32 KB, XOR-swizzled (T2)
  const int tile = blockIdx.x % 313;
  const int rg   = blockIdx.x / 313;
  const int m0   = tile * 64;
  const int tid  = threadIdx.x;
  const int wave = tid >> 6, lane = tid & 63;
  const int lrow = lane & 15;
  const int lk   = (lane >> 4) * 8;
  // A fragments in registers (MFMA lane layout, straight from L2-hot hb)
  short8 a[4];
  const int arow = m0 + wave * 16 + lrow;
  const short8 az = __builtin_bit_cast(short8, make_int4(0, 0, 0, 0));
  #pragma unroll
  for (int ks = 0; ks < 4; ++ks)
    a[ks] = (arow < N_NODES)
          ? *(const short8*)(hb + (size_t)arow * 128 + ks * 32 + lk) : az;
  const int trow = tid >> 4;                     // 0..15 staging row base
  const int tch  = tid & 15;                     // 16B-chunk index 0..15
  for (int rb = 0; rb < RB; ++rb){
    const int r = rg * RB + rb;
    __syncthreads();                             // prior-phase B reads done
    #pragma unroll
    for (int it = 0; it < 8; ++it){              // stage B_r swizzled
      int rl = trow + it * 16;
      int4 b = *(const int4*)(wrelT + ((size_t)r * 128 + rl) * 128 + tch * 8);
      *(int4*)((char*)Bs + rl * 256 + ((tch ^ (rl & 7)) * 16)) = b;
    }
    __syncthreads();
    floatx4 acc[8] = {};
    #pragma unroll
    for (int ks = 0; ks < 4; ++ks){
      #pragma unroll
      for (int nf = 0; nf < 8; ++nf){
        int brow = nf * 16 + lrow;
        int bch  = (ks * 4 + (lk >> 3)) ^ (brow & 7);
        short8 b = *(const short8*)((const char*)Bs + brow * 256 + bch * 16);
        acc[nf] = __builtin_amdgcn_mfma_f32_16x16x32_bf16(a[ks], b, acc[nf], 0, 0, 0);
      }
    }
    // direct bf16 stores (C/D: row=(l>>4)*4+j, col=l&15)
    const size_t rbase = (size_t)r * N_NODES;
    #pragma unroll
    for (int nf = 0; nf < 8; ++nf){
      int col = nf * 16 + lrow;
      #pragma unroll
      for (int j = 0; j < 4; ++j){
        int row = m0 + wave * 16 + ((lane >> 4) << 2) + j;
        if (row < N_NODES)
          xW[(rbase + row) * 128 + col] = f2bf(acc[nf][j]);
      }
    }
  }
}

// ---------------- K3: gather + segment-sum + relu (16-deep MLP, 4 nodes/blk) -
__global__ __launch_bounds__(256) void k_agg(const int* __restrict__ offsets,
    const int* __restrict__ gidx, const u16* __restrict__ xW, float* __restrict__ out){
  const int n = blockIdx.x * 4 + (threadIdx.x >> 6);
  const int t = threadIdx.x & 63;                // owns channels 2t, 2t+1
  const int b0 = offsets[n], b1 = offsets[n + 1];
  float2 a[16];
  #pragma unroll
  for (int j = 0; j < 16; ++j) a[j] = make_float2(0.f, 0.f);
  int e = b0;
  for (; e + 16 <= b1; e += 16){
    int g[16];
    #pragma unroll
    for (int j = 0; j < 16; ++j) g[j] = gidx[e + j];
    #pragma unroll
    for (int j = 0; j < 16; ++j){
      u32 pk = *(const u32*)(xW + (size_t)g[j] * 128 + t * 2);
      a[j].x += bf2f((u16)(pk & 0xffffu));
      a[j].y += bf2f((u16)(pk >> 16));
    }
  }
  for (; e < b1; ++e){
    int g = gidx[e];
    u32 pk = *(const u32*)(xW + (size_t)g * 128 + t * 2);
    a[0].x += bf2f((u16)(pk & 0xffffu));
    a[0].y += bf2f((u16)(pk >> 16));
  }
  float2 s = make_float2(0.f, 0.f);
  #pragma unroll
  for (int j = 0; j < 16; ++j){ s.x += a[j].x; s.y += a[j].y; }
  *(float2*)(out + (size_t)n * 128 + t * 2) =
      make_float2(fmaxf(s.x, 0.f), fmaxf(s.y, 0.f));
}

// ---------------- launcher ---------------------------------------------------
extern "C" void kernel_launch(void* const* d_in, const int* in_sizes, int n_in,
                              void* d_out, int out_size, void* d_ws, size_t ws_size,
                              hipStream_t stream){
  const float* h      = (const float*)d_in[0];
  const float* weight = (const float*)d_in[1];
  const float* w_comp = (const float*)d_in[2];
  const int* src      = (const int*)d_in[3];
  const int* dst      = (const int*)d_in[4];
  const int* etype    = (const int*)d_in[5];
  float* out = (float*)d_out;

  char* p = (char*)d_ws;
  u16* xW      = (u16*)p;  p += 102400000;       // [20][20000][128] bf16
  u16* hb      = (u16*)p;  p += 5120000;
  u16* wrelT   = (u16*)p;  p += 655360;
  int* counts  = (int*)p;  p += 80000;
  int* offs    = (int*)p;  p += 80128;           // 20001 ints + pad
  int* rank    = (int*)p;  p += 2560000;
  int* gidx    = (int*)p;  /* 2,560,000 B */     // total ~113.5 MB

  hipMemsetAsync(counts, 0, N_NODES * sizeof(int), stream);
  k_prep<<<dim3(3780), dim3(256), 0, stream>>>(h, hb, dst, counts, rank,
                                               weight, w_comp, wrelT);
  k_scan<<<dim3(1), dim3(1024), 0, stream>>>(counts, offs);
  k_gemm_fill<<<dim3(GEMM_BLOCKS + FILL_BLOCKS), dim3(256), 0, stream>>>(
      hb, wrelT, xW, dst, src, etype, offs, rank, gidx);
  k_agg<<<dim3(N_NODES / 4), dim3(256), 0, stream>>>(offs, gidx, xW, out);
}